// Round 2
// baseline (587.812 us; speedup 1.0000x reference)
//
#include <hip/hip_runtime.h>
#include <cstdint>
#include <cstddef>

#define MDIM 8192
#define NDIM 4096
#define KDIM 4096

typedef __attribute__((ext_vector_type(8))) __bf16 bf16x8;
typedef __attribute__((ext_vector_type(16))) float floatx16;

typedef __attribute__((address_space(3))) void lds_t;
typedef __attribute__((address_space(1))) void glb_t;

__device__ __forceinline__ unsigned short f32_to_bf16(float f) {
  unsigned int u = __float_as_uint(f);
  u += 0x7FFFu + ((u >> 16) & 1u);   // RNE
  return (unsigned short)(u >> 16);
}

// e2m1 magnitude for code c in 0..7: {0,0.5,1,1.5,2,3,4,6}
__device__ __forceinline__ float fp4_mag(int c) {
  int e = (c >> 1) & 3, m = c & 1;
  int sh = e ? (e - 1) : 0;
  return e ? 0.5f * (float)((2 + m) << sh) : 0.5f * (float)m;
}

// ---------------- merged prepass: x fp32->bf16  +  weight dequant ----------------
// blocks [0, 8192):   x conversion, 16 elems/thread
// blocks [8192,10240): dequant, 2 scale-blocks (32 weights)/thread
__global__ __launch_bounds__(256) void prep_kernel(const float* __restrict__ x,
                                                   unsigned short* __restrict__ xb,
                                                   const int* __restrict__ packed,
                                                   const float* __restrict__ scales,
                                                   unsigned short* __restrict__ wb) {
  if (blockIdx.x < 8192) {
    const int t = blockIdx.x * 256 + threadIdx.x;       // 0 .. 2097151, 16 elems each
    const float4* src = (const float4*)x + (size_t)t * 4;
    float4 a = src[0], b = src[1], c = src[2], d = src[3];
    union { unsigned short us[16]; uint4 u4[2]; } o;
    o.us[0]  = f32_to_bf16(a.x); o.us[1]  = f32_to_bf16(a.y);
    o.us[2]  = f32_to_bf16(a.z); o.us[3]  = f32_to_bf16(a.w);
    o.us[4]  = f32_to_bf16(b.x); o.us[5]  = f32_to_bf16(b.y);
    o.us[6]  = f32_to_bf16(b.z); o.us[7]  = f32_to_bf16(b.w);
    o.us[8]  = f32_to_bf16(c.x); o.us[9]  = f32_to_bf16(c.y);
    o.us[10] = f32_to_bf16(c.z); o.us[11] = f32_to_bf16(c.w);
    o.us[12] = f32_to_bf16(d.x); o.us[13] = f32_to_bf16(d.y);
    o.us[14] = f32_to_bf16(d.z); o.us[15] = f32_to_bf16(d.w);
    uint4* dst = (uint4*)xb + (size_t)t * 2;
    dst[0] = o.u4[0]; dst[1] = o.u4[1];
  } else {
    const int u = (blockIdx.x - 8192) * 256 + threadIdx.x;  // 0 .. 524287
    const int4* p = (const int4*)packed + (size_t)u * 4;    // 2 scale-blocks = 16 bytes-as-int32 x 1? (4 int4)
    int4 p0 = p[0], p1 = p[1], p2 = p[2], p3 = p[3];
    float s0 = scales[2 * u], s1 = scales[2 * u + 1];
    int bytes[16] = {p0.x, p0.y, p0.z, p0.w, p1.x, p1.y, p1.z, p1.w,
                     p2.x, p2.y, p2.z, p2.w, p3.x, p3.y, p3.z, p3.w};
    union { unsigned short us[32]; uint4 u4[4]; } o;
#pragma unroll
    for (int i = 0; i < 16; ++i) {
      float s = (i < 8) ? s0 : s1;
      int by = bytes[i] & 255;
      int hi = by >> 4, lo = by & 15;                     // even idx = high nibble
      float vh = fp4_mag(hi & 7) * s; if (hi & 8) vh = -vh;
      float vl = fp4_mag(lo & 7) * s; if (lo & 8) vl = -vl;
      o.us[2 * i]     = f32_to_bf16(vh);
      o.us[2 * i + 1] = f32_to_bf16(vl);
    }
    uint4* dst = (uint4*)wb + (size_t)u * 4;
    dst[0] = o.u4[0]; dst[1] = o.u4[1]; dst[2] = o.u4[2]; dst[3] = o.u4[3];
  }
}

// ---------------- main GEMM: C[M,N] = A[M,K] * B[N,K]^T + bias ----------------
// 128x128 block tile, BK=32, 4 waves x (2x2) 32x32x16 bf16 MFMA.
// global_load_lds width-16 staging; LDS tiles row-major 128x32 UNPADDED.
__global__ __launch_bounds__(256, 3) void gemm_kernel(const __bf16* __restrict__ A,
                                                      const __bf16* __restrict__ B,
                                                      const float* __restrict__ bias,
                                                      float* __restrict__ C) {
  __shared__ __bf16 As[128 * 32];
  __shared__ __bf16 Bs[128 * 32];
  const int t = threadIdx.x;
  const int wave = t >> 6, lane = t & 63;
  const int r32 = lane & 31, half = lane >> 5;
  const int wm = (wave >> 1) * 64, wn = (wave & 1) * 64;
  const int m0 = blockIdx.y * 128, n0 = blockIdx.x * 128;

  floatx16 acc[2][2] = {};

  // staging map: flat id t covers tile row t>>2, cols (t&3)*8 ; LDS byte t*16
  const int sr = t >> 2;            // 0..63
  const int sc = (t & 3) * 8;       // 0,8,16,24

  const __bf16* ga = A + (size_t)(m0 + sr) * KDIM + sc;
  const __bf16* gb = B + (size_t)(n0 + sr) * KDIM + sc;

  for (int k0 = 0; k0 < KDIM; k0 += 32) {
    __builtin_amdgcn_global_load_lds((const glb_t*)(ga),
                                     (lds_t*)(As + wave * 512), 16, 0, 0);
    __builtin_amdgcn_global_load_lds((const glb_t*)(ga + (size_t)64 * KDIM),
                                     (lds_t*)(As + 2048 + wave * 512), 16, 0, 0);
    __builtin_amdgcn_global_load_lds((const glb_t*)(gb),
                                     (lds_t*)(Bs + wave * 512), 16, 0, 0);
    __builtin_amdgcn_global_load_lds((const glb_t*)(gb + (size_t)64 * KDIM),
                                     (lds_t*)(Bs + 2048 + wave * 512), 16, 0, 0);
    ga += 32; gb += 32;
    __syncthreads();

#pragma unroll
    for (int kh = 0; kh < 2; ++kh) {
      bf16x8 af[2], bfr[2];
#pragma unroll
      for (int i = 0; i < 2; ++i) {
        // A-operand 32x32x16: lane holds A[m = lane&31][k = (lane>>5)*8 + j]
        af[i]  = *(const bf16x8*)(As + (wm + i * 32 + r32) * 32 + kh * 16 + half * 8);
        // B-operand mirrors A with B stored [n][k]
        bfr[i] = *(const bf16x8*)(Bs + (wn + i * 32 + r32) * 32 + kh * 16 + half * 8);
      }
#pragma unroll
      for (int i = 0; i < 2; ++i)
#pragma unroll
        for (int j = 0; j < 2; ++j)
          acc[i][j] = __builtin_amdgcn_mfma_f32_32x32x16_bf16(af[i], bfr[j], acc[i][j], 0, 0, 0);
    }
    __syncthreads();
  }

  // epilogue: 32x32 C/D layout: col = lane&31, row = (reg&3) + 8*(reg>>2) + 4*(lane>>5)
  float bv[2];
#pragma unroll
  for (int j = 0; j < 2; ++j) bv[j] = bias[n0 + wn + j * 32 + r32];
#pragma unroll
  for (int i = 0; i < 2; ++i)
#pragma unroll
    for (int j = 0; j < 2; ++j) {
      const int gc = n0 + wn + j * 32 + r32;
#pragma unroll
      for (int r = 0; r < 16; ++r) {
        const int gr = m0 + wm + i * 32 + (r & 3) + 8 * (r >> 2) + 4 * half;
        C[(size_t)gr * NDIM + gc] = acc[i][j][r] + bv[j];
      }
    }
}

// ---------------- fallback (ws too small): fused naive ----------------
__global__ __launch_bounds__(256) void fused_fallback(const float* __restrict__ x,
                                                      const int* __restrict__ packed,
                                                      const float* __restrict__ scales,
                                                      const float* __restrict__ bias,
                                                      float* __restrict__ out) {
  const int n = blockIdx.x * 256 + threadIdx.x;
  const int m = blockIdx.y;
  const float* xr = x + (size_t)m * KDIM;
  const int* pr = packed + (size_t)n * (KDIM / 2);
  const float* sc = scales + (size_t)n * (KDIM / 16);
  float acc = 0.f;
  for (int kb = 0; kb < KDIM / 16; ++kb) {
    float s = sc[kb];
    float part = 0.f;
#pragma unroll
    for (int i = 0; i < 8; ++i) {
      int by = pr[kb * 8 + i] & 255;
      int hi = by >> 4, lo = by & 15;
      float vh = fp4_mag(hi & 7); if (hi & 8) vh = -vh;
      float vl = fp4_mag(lo & 7); if (lo & 8) vl = -vl;
      part += xr[kb * 16 + 2 * i] * vh + xr[kb * 16 + 2 * i + 1] * vl;
    }
    acc += s * part;
  }
  out[(size_t)m * NDIM + n] = acc + bias[n];
}

extern "C" void kernel_launch(void* const* d_in, const int* in_sizes, int n_in,
                              void* d_out, int out_size, void* d_ws, size_t ws_size,
                              hipStream_t stream) {
  const float* x      = (const float*)d_in[0];
  const int*   packed = (const int*)d_in[1];
  const float* scales = (const float*)d_in[2];
  const float* bias   = (const float*)d_in[3];
  float* out = (float*)d_out;

  const size_t needA = (size_t)MDIM * KDIM * 2;   // 64 MB bf16 x
  const size_t needW = (size_t)NDIM * KDIM * 2;   // 32 MB bf16 w

  if (ws_size >= needA + needW) {
    unsigned short* xb = (unsigned short*)d_ws;
    unsigned short* wb = (unsigned short*)((char*)d_ws + needA);
    prep_kernel<<<10240, 256, 0, stream>>>(x, xb, packed, scales, wb);
    dim3 grid(NDIM / 128, MDIM / 128);
    gemm_kernel<<<grid, 256, 0, stream>>>((const __bf16*)xb, (const __bf16*)wb, bias, out);
  } else {
    dim3 grid(NDIM / 256, MDIM);
    fused_fallback<<<grid, 256, 0, stream>>>(x, packed, scales, bias, out);
  }
}